// Round 8
// baseline (265.874 us; speedup 1.0000x reference)
//
#include <hip/hip_runtime.h>
#include <math.h>

typedef unsigned short u16;
typedef __bf16 bf16x8 __attribute__((ext_vector_type(8)));
typedef u16    u16x8  __attribute__((ext_vector_type(8)));
typedef float  f32x4  __attribute__((ext_vector_type(4)));
typedef float  f32x16 __attribute__((ext_vector_type(16)));

__device__ __forceinline__ float b2f(u16 u) {
    union { unsigned u; float f; } x; x.u = ((unsigned)u) << 16; return x.f;
}
__device__ __forceinline__ u16 f2b(float f) {
    union { float f; unsigned u; } x; x.f = f;
    unsigned r = x.u + 0x7FFFu + ((x.u >> 16) & 1u);   // RNE
    return (u16)(r >> 16);
}
__device__ __forceinline__ f32x4 mfma16(bf16x8 a, bf16x8 b, f32x4 c) {
    return __builtin_amdgcn_mfma_f32_16x16x32_bf16(a, b, c, 0, 0, 0);
}
__device__ __forceinline__ f32x16 mfma32(bf16x8 a, bf16x8 b, f32x16 c) {
    return __builtin_amdgcn_mfma_f32_32x32x16_bf16(a, b, c, 0, 0, 0);
}
__device__ __forceinline__ void dma16(const void* g, void* l) {
    __builtin_amdgcn_global_load_lds((const __attribute__((address_space(1))) void*)g,
                                     (__attribute__((address_space(3))) void*)l, 16, 0, 0);
}
// per-wave dtype vote on 64 fixed words: 1 = fp32, 0 = bf16
__device__ __forceinline__ int dtype_vote(const unsigned* w) {
    unsigned v = w[threadIdx.x & 63];
    unsigned e = ((v & 0xFFFFu) >> 7) & 0xFFu;
    unsigned long long m = __ballot(e >= 0x60u && e <= 0x8Fu);
    return (__popcll(m) >= 32) ? 0 : 1;
}

#define QSCALE 0.09016844f   // (1/16) * log2(e): softmax in base-2 domain

// ---------------------------------------------------------------- fused convert: x (blocks <4096) + params (>=4096)
__global__ __launch_bounds__(256) void k_cvt(const void* __restrict__ xsrc, u16* __restrict__ xdst,
                                             int* __restrict__ flag, float2* __restrict__ part,
                                             const void* s0, const void* s1, const void* s2,
                                             const void* s3, const void* s4, const void* s5,
                                             u16* d0, u16* d1, u16* d2, u16* d3, u16* d4, u16* d5) {
    if (blockIdx.x >= 4096) {
        const int f = dtype_vote((const unsigned*)s2);
        const int i = (blockIdx.x - 4096) * 256 + threadIdx.x;
        const void* s; u16* d; int j;
        if      (i < 256)    { s = s0; d = d0; j = i; }
        else if (i < 512)    { s = s1; d = d1; j = i - 256; }
        else if (i < 197120) { s = s2; d = d2; j = i - 512; }
        else if (i < 197888) { s = s3; d = d3; j = i - 197120; }
        else if (i < 263424) { s = s4; d = d4; j = i - 197888; }
        else if (i < 263680) { s = s5; d = d5; j = i - 263424; }
        else return;
        if (f) d[j] = f2b(((const float*)s)[j]);
        else   d[j] = ((const u16*)s)[j];
        return;
    }
    const int f = dtype_vote((const unsigned*)xsrc);
    if (blockIdx.x == 0 && threadIdx.x == 0) *flag = f;
    const int i = (blockIdx.x * 256 + threadIdx.x) * 4;
    u16 o[4];
    if (f) {
        float4 v = *(const float4*)((const float*)xsrc + i);
        o[0] = f2b(v.x); o[1] = f2b(v.y); o[2] = f2b(v.z); o[3] = f2b(v.w);
    } else {
        uint2 v = *(const uint2*)((const u16*)xsrc + i);
        o[0] = (u16)(v.x & 0xFFFF); o[1] = (u16)(v.x >> 16);
        o[2] = (u16)(v.y & 0xFFFF); o[3] = (u16)(v.y >> 16);
    }
    unsigned lo = (unsigned)o[0] | ((unsigned)o[1] << 16);
    unsigned hi = (unsigned)o[2] | ((unsigned)o[3] << 16);
    *(uint2*)(xdst + i) = make_uint2(lo, hi);
    float s = 0.f, ss = 0.f;
#pragma unroll
    for (int e = 0; e < 4; e++) { float x = b2f(o[e]); s += x; ss += x * x; }
#pragma unroll
    for (int d = 1; d < 64; d <<= 1) { s += __shfl_xor(s, d, 64); ss += __shfl_xor(ss, d, 64); }
    __shared__ float rs[4], rss[4];
    const int wv = threadIdx.x >> 6;
    if ((threadIdx.x & 63) == 0) { rs[wv] = s; rss[wv] = ss; }
    __syncthreads();
    if (threadIdx.x == 0)
        part[blockIdx.x] = make_float2(rs[0] + rs[1] + rs[2] + rs[3],
                                       rss[0] + rss[1] + rss[2] + rss[3]);
}

// ---------------------------------------------------------------- finalize group-norm stats
__global__ __launch_bounds__(64) void k_statsf(const float2* __restrict__ part, float* __restrict__ stats) {
    const int g = blockIdx.x, lane = threadIdx.x;
    float2 a = part[g * 128 + lane], b = part[g * 128 + 64 + lane];
    float s = a.x + b.x, ss = a.y + b.y;
#pragma unroll
    for (int d = 1; d < 64; d <<= 1) { s += __shfl_xor(s, d, 64); ss += __shfl_xor(ss, d, 64); }
    if (lane == 0) {
        float mean = s * (1.f / 131072.f);
        float var = fmaxf(ss * (1.f / 131072.f) - mean * mean, 0.f);
        stats[g] = mean;
        stats[32 + g] = rsqrtf(var + 1e-5f);
    }
}

// ---------------------------------------------------------------- normalize + transpose to tokens [b][n][c]
__global__ __launch_bounds__(256) void k_tok(const u16* __restrict__ x, const u16* __restrict__ nw,
                                             const u16* __restrict__ nb, const float* __restrict__ stats,
                                             u16* __restrict__ tok) {
    const int b = blockIdx.z, c0 = blockIdx.y * 64, p0 = blockIdx.x * 64;
    __shared__ u16 t[64][72];
    const int cl = threadIdx.x >> 2, seg = threadIdx.x & 3;
    const int c = c0 + cl;
    const int g = c >> 5;
    const float mean = stats[b * 8 + g], rstd = stats[32 + b * 8 + g];
    const float scale = b2f(nw[c]) * rstd;
    const float shift = b2f(nb[c]) - mean * scale;
    const u16* xp = x + ((size_t)(b * 256 + c)) * 4096 + p0 + seg * 16;
#pragma unroll
    for (int h = 0; h < 2; h++) {
        bf16x8 v = *(const bf16x8*)(xp + h * 8);
#pragma unroll
        for (int j = 0; j < 8; j++)
            t[seg * 16 + h * 8 + j][cl] = f2b((float)v[j] * scale + shift);
    }
    __syncthreads();
    u16x8 o0, o1;
#pragma unroll
    for (int j = 0; j < 8; j++) { o0[j] = t[cl][seg * 16 + j]; o1[j] = t[cl][seg * 16 + 8 + j]; }
    u16* op = tok + ((size_t)(b * 4096 + p0 + cl)) * 256 + c0 + seg * 16;
    *(u16x8*)op = o0;
    *((u16x8*)op + 1) = o1;
}

// ---------------------------------------------------------------- QKV GEMM, coalesced LDS-transposed epilogue
__global__ __launch_bounds__(256) void k_qkv(const u16* __restrict__ A, const u16* __restrict__ W,
                                             const u16* __restrict__ bias,
                                             u16* __restrict__ Qo, u16* __restrict__ Ko, u16* __restrict__ Vt) {
    const int m0 = blockIdx.x * 128, n0 = blockIdx.y * 128;
    const int cls = blockIdx.y >> 1, sub = (blockIdx.y & 1) * 128;
    const int b = m0 >> 12, p0 = m0 & 4095;
    const int tid = threadIdx.x, w = tid >> 6, lane = tid & 63, l15 = lane & 15, l4 = lane >> 4;
    const int wm = w >> 1, wn = w & 1;
    __shared__ __attribute__((aligned(16))) char QL[32768];
    u16* At = (u16*)QL;              // [128][64]
    u16* Bt = (u16*)(QL + 16384);    // [128][64]
    u16* E  = (u16*)QL;              // [128][128] epilogue reuse
    f32x4 acc[4][4];
    const f32x4 z = {0.f, 0.f, 0.f, 0.f};
#pragma unroll
    for (int i = 0; i < 4; i++)
#pragma unroll
        for (int j = 0; j < 4; j++) acc[i][j] = z;

    for (int kt = 0; kt < 4; kt++) {
        const int k0 = kt * 64;
#pragma unroll
        for (int i = 0; i < 4; i++) {
            int v = tid + i * 256;
            int row = v >> 3, c8 = v & 7;
            int swz = (c8 ^ (row & 7)) << 3;
            *(u16x8*)(&At[row * 64 + swz]) = *(const u16x8*)(A + (size_t)(m0 + row) * 256 + k0 + c8 * 8);
            *(u16x8*)(&Bt[row * 64 + swz]) = *(const u16x8*)(W + (size_t)(n0 + row) * 256 + k0 + c8 * 8);
        }
        __syncthreads();
#pragma unroll
        for (int ks = 0; ks < 2; ks++) {
            const int sc = ((ks * 4 + l4) ^ (l15 & 7)) << 3;
            bf16x8 af[4], bfr[4];
#pragma unroll
            for (int i = 0; i < 4; i++) {
                af[i]  = *(const bf16x8*)(&At[(wm * 64 + i * 16 + l15) * 64 + sc]);
                bfr[i] = *(const bf16x8*)(&Bt[(wn * 64 + i * 16 + l15) * 64 + sc]);
            }
#pragma unroll
            for (int i = 0; i < 4; i++)
#pragma unroll
                for (int j = 0; j < 4; j++) acc[i][j] = mfma16(af[i], bfr[j], acc[i][j]);
        }
        __syncthreads();
    }

    const float sf = (cls == 0) ? QSCALE : 1.f;
#pragma unroll
    for (int j = 0; j < 4; j++) {
        const int nl = wn * 64 + j * 16 + l15;
        const float bia = b2f(bias[n0 + nl]);
#pragma unroll
        for (int i = 0; i < 4; i++) {
#pragma unroll
            for (int r = 0; r < 4; r++) {
                const int ml = wm * 64 + i * 16 + l4 * 4 + r;
                const u16 val = f2b((acc[i][j][r] + bia) * sf);
                if (cls < 2) {
                    E[ml * 128 + (((nl >> 3) ^ (ml & 7)) << 3) + (nl & 7)] = val;
                } else {
                    int ps = ml ^ ((((ml >> 2) ^ (ml >> 3)) & 1) * 12);   // swap bits 2<->3
                    E[nl * 128 + (((ps >> 3) ^ (nl & 7)) << 3) + (ps & 7)] = val;
                }
            }
        }
    }
    __syncthreads();
    const int row = tid >> 1, half = tid & 1;
    u16* dst = (cls == 0) ? (Qo + (size_t)(m0 + row) * 256 + sub)
             : (cls == 1) ? (Ko + (size_t)(m0 + row) * 256 + sub)
                          : (Vt + (size_t)(b * 256 + sub + row) * 4096 + p0);
#pragma unroll
    for (int k = 0; k < 8; k++) {
        const int chunk = half * 8 + k;
        u16x8 v = *(const u16x8*)(&E[row * 128 + ((chunk ^ (row & 7)) << 3)]);
        *(u16x8*)(dst + chunk * 8) = v;
    }
}

// ---------------------------------------------------------------- flash attention: S^T trick, sync staging, [c][q] epilogue (r5 = 87us)
// grid (32 qtiles x128q, 4 b, 4 splits); block 256 = 4 waves x 32 q; Bc=32; 32 iters.
__global__ __launch_bounds__(256, 2) void k_attn(const u16* __restrict__ Q, const u16* __restrict__ K,
                                                 const u16* __restrict__ Vt,
                                                 u16* __restrict__ Up, float* __restrict__ ml) {
    const int qt = blockIdx.x, b = blockIdx.y, sp = blockIdx.z;
    const int tid = threadIdx.x, w = tid >> 6, lane = tid & 63;
    const int l31 = lane & 31, h = lane >> 5;
    const int qcol = qt * 128 + w * 32 + l31;

    __shared__ __attribute__((aligned(16))) u16 KT[32 * 256];   // [j][c] swizzled
    __shared__ __attribute__((aligned(16))) u16 VT[256 * 32];   // [c][t] swizzled

    bf16x8 aq[16];
    {
        const u16* qp = Q + ((size_t)(b * 4096 + qcol)) * 256 + h * 8;
#pragma unroll
        for (int kb = 0; kb < 16; kb++) aq[kb] = *(const bf16x8*)(qp + kb * 16);
    }
    f32x16 acc[8];
#pragma unroll
    for (int ct = 0; ct < 8; ct++)
#pragma unroll
        for (int r = 0; r < 16; r++) acc[ct][r] = 0.f;
    float m_i = -3e38f, l_i = 0.f;

    const u16* Kg0 = K + (size_t)(b * 4096 + sp * 1024) * 256;
    const u16* Vg0 = Vt + (size_t)b * 256 * 4096 + sp * 1024;
    const int wb = (tid & 192) * 8;

    for (int kt = 0; kt < 32; kt++) {
        {
            const u16* Kg = Kg0 + (size_t)kt * 32 * 256;
#pragma unroll
            for (int i = 0; i < 4; i++) {
                int q = i * 256 + tid;
                int row = q >> 5, c = q & 31;
                dma16(Kg + row * 256 + ((c ^ row) << 3), &KT[i * 2048 + wb]);
            }
            const u16* Vg = Vg0 + kt * 32;
#pragma unroll
            for (int i = 0; i < 4; i++) {
                int q = i * 256 + tid;
                int row = q >> 2, c = q & 3;
                dma16(Vg + (size_t)row * 4096 + ((c ^ ((row >> 3) & 3)) << 3), &VT[i * 2048 + wb]);
            }
        }
        __syncthreads();

        // ---- S^T = K Q^T
        f32x16 st;
#pragma unroll
        for (int r = 0; r < 16; r++) st[r] = 0.f;
#pragma unroll
        for (int kb = 0; kb < 16; kb++) {
            bf16x8 bk = *(const bf16x8*)(&KT[l31 * 256 + (((kb * 2 + h) ^ l31) << 3)]);
            st = mfma32(bk, aq[kb], st);
        }

        // ---- per-lane online softmax (base-2 domain)
        float mx = st[0];
#pragma unroll
        for (int r = 1; r < 16; r++) mx = fmaxf(mx, st[r]);
        mx = fmaxf(mx, __shfl_xor(mx, 32, 64));
        if (__any(mx > m_i + 4.f)) {
            const float m_new = fmaxf(m_i, mx);
            const float al = __builtin_amdgcn_exp2f(m_i - m_new);
#pragma unroll
            for (int ct = 0; ct < 8; ct++)
#pragma unroll
                for (int r = 0; r < 16; r++) acc[ct][r] *= al;
            l_i *= al;
            m_i = m_new;
        }
        float sum = 0.f;
#pragma unroll
        for (int r = 0; r < 16; r++) {
            st[r] = __builtin_amdgcn_exp2f(st[r] - m_i);
            sum += st[r];
        }
        sum += __shfl_xor(sum, 32, 64);
        l_i += sum;

        union { u16x8 u; bf16x8 bv; } p0, p1;
#pragma unroll
        for (int e = 0; e < 8; e++) { p0.u[e] = f2b(st[e]); p1.u[e] = f2b(st[8 + e]); }

        // ---- acc += V^T P^T
#pragma unroll
        for (int ct = 0; ct < 8; ct++) {
            bf16x8 av0 = *(const bf16x8*)(&VT[(ct * 32 + l31) * 32 + ((h ^ (l31 >> 3)) << 3)]);
            acc[ct] = mfma32(av0, p0.bv, acc[ct]);
            bf16x8 av1 = *(const bf16x8*)(&VT[(ct * 32 + l31) * 32 + (((2 + h) ^ (l31 >> 3)) << 3)]);
            acc[ct] = mfma32(av1, p1.bv, acc[ct]);
        }
        __syncthreads();
    }

    // ---- epilogue: (m,l) + unnormalized partial O^T [c][q] (64B-coalesced per half-wave)
    if (h == 0)
        ((float2*)ml)[(size_t)(sp * 4 + b) * 4096 + qcol] = make_float2(m_i, l_i);
    u16* up = Up + (size_t)(sp * 4 + b) * 256 * 4096 + qcol;
#pragma unroll
    for (int ct = 0; ct < 8; ct++) {
#pragma unroll
        for (int r = 0; r < 16; r++) {
            const int c = ct * 32 + (r & 3) + 8 * (r >> 2) + 4 * h;
            up[(size_t)c * 4096] = f2b(acc[ct][r]);
        }
    }
}

// ---------------------------------------------------------------- proj GEMM: fused ml-combine (from Up[c][q]) + residual
// grid (256): 64 m-rows x full N=256 per block.
__global__ __launch_bounds__(256) void k_proj(const u16* __restrict__ Up, const float* __restrict__ ml,
                                              const u16* __restrict__ W, const u16* __restrict__ bias,
                                              const u16* __restrict__ x, void* __restrict__ out,
                                              const int* __restrict__ flag) {
    const int f32out = *flag;
    const int m0 = blockIdx.x * 64;
    const int b = m0 >> 12, q0 = m0 & 4095;
    const int tid = threadIdx.x, w = tid >> 6, lane = tid & 63, l15 = lane & 15, l4 = lane >> 4;
    const int wm = w >> 1, wn = w & 1;
    __shared__ __attribute__((aligned(16))) char PL[40960];
    u16* At = (u16*)PL;            // [64][64]
    u16* Bt = (u16*)(PL + 8192);   // [256][64]
    u16* Ot = (u16*)PL;            // [256][64] epilogue reuse
    __shared__ float4 W4s[64];

    if (tid < 64) {
        const int q = q0 + tid;
        float m_s[4], l_s[4];
#pragma unroll
        for (int s = 0; s < 4; s++) {
            float2 v = ((const float2*)ml)[(size_t)(s * 4 + b) * 4096 + q];
            m_s[s] = v.x; l_s[s] = v.y;
        }
        float M = fmaxf(fmaxf(m_s[0], m_s[1]), fmaxf(m_s[2], m_s[3]));
        float L = 0.f, e[4];
#pragma unroll
        for (int s = 0; s < 4; s++) { e[s] = __builtin_amdgcn_exp2f(m_s[s] - M); L += l_s[s] * e[s]; }
        float inv = 1.f / fmaxf(L, 1e-30f);
        W4s[tid] = make_float4(e[0] * inv, e[1] * inv, e[2] * inv, e[3] * inv);
    }
    __syncthreads();

    // per-thread: q = q0 + (tid&63) fixed; handles 16 c per kt
    const int q_l = tid & 63, cseg = tid >> 6;
    const float4 wq = W4s[q_l];
    const float wsv[4] = {wq.x, wq.y, wq.z, wq.w};
    const u16* upq = Up + q0 + q_l;

    f32x4 acc[2][8];
    const f32x4 z = {0.f, 0.f, 0.f, 0.f};
#pragma unroll
    for (int i = 0; i < 2; i++)
#pragma unroll
        for (int j = 0; j < 8; j++) acc[i][j] = z;

    for (int kt = 0; kt < 4; kt++) {
        const int k0 = kt * 64;
        // ---- A-staging: combine 4 splits from Up[c][q] (coalesced scalar loads along q)
#pragma unroll
        for (int cc = 0; cc < 16; cc++) {
            const int c = cseg * 16 + cc;
            float v = 0.f;
#pragma unroll
            for (int s = 0; s < 4; s++)
                v += b2f(upq[(size_t)((s * 4 + b) * 256 + k0 + c) * 4096]) * wsv[s];
            At[q_l * 64 + (((c >> 3) ^ (q_l & 7)) << 3) + (c & 7)] = f2b(v);
        }
        // ---- B-staging: proj_w [256][64]
#pragma unroll
        for (int i = 0; i < 8; i++) {
            int v = i * 256 + tid;
            int row = v >> 3, c8 = v & 7;
            *(u16x8*)(&Bt[row * 64 + ((c8 ^ (row & 7)) << 3)]) =
                *(const u16x8*)(W + (size_t)row * 256 + k0 + c8 * 8);
        }
        __syncthreads();
#pragma unroll
        for (int ks = 0; ks < 2; ks++) {
            const int sc = ((ks * 4 + l4) ^ (l15 & 7)) << 3;
            bf16x8 af[2], bfr[8];
#pragma unroll
            for (int i = 0; i < 2; i++)
                af[i] = *(const bf16x8*)(&At[(wm * 32 + i * 16 + l15) * 64 + sc]);
#pragma unroll
            for (int j = 0; j < 8; j++)
                bfr[j] = *(const bf16x8*)(&Bt[(wn * 128 + j * 16 + l15) * 64 + sc]);
#pragma unroll
            for (int i = 0; i < 2; i++)
#pragma unroll
                for (int j = 0; j < 8; j++) acc[i][j] = mfma16(af[i], bfr[j], acc[i][j]);
        }
        __syncthreads();
    }

#pragma unroll
    for (int j = 0; j < 8; j++) {
        const int n = wn * 128 + j * 16 + l15;
        const float bia = b2f(bias[n]);
#pragma unroll
        for (int i = 0; i < 2; i++) {
#pragma unroll
            for (int r = 0; r < 4; r++) {
                const int p = wm * 32 + i * 16 + l4 * 4 + r;
                Ot[n * 64 + ((((p >> 3) ^ (n & 7)) << 3)) + (p & 7)] = f2b(acc[i][j][r] + bia);
            }
        }
    }
    __syncthreads();
    const int ps = (tid & 7) * 8;
#pragma unroll
    for (int v = 0; v < 8; v++) {
        const int n = v * 32 + (tid >> 3);
        u16x8 d = *(const u16x8*)(&Ot[n * 64 + ((((ps >> 3) ^ (n & 7)) << 3))]);
        const size_t base = ((size_t)(b * 256 + n)) * 4096 + q0 + ps;
        u16x8 xv = *(const u16x8*)(x + base);
        if (f32out) {
            float4 o0, o1;
#pragma unroll
            for (int e = 0; e < 4; e++) o0[e] = b2f(d[e]) + b2f(xv[e]);
#pragma unroll
            for (int e = 0; e < 4; e++) o1[e] = b2f(d[4 + e]) + b2f(xv[4 + e]);
            *(float4*)((float*)out + base) = o0;
            *(float4*)((float*)out + base + 4) = o1;
        } else {
            u16x8 o;
#pragma unroll
            for (int e = 0; e < 8; e++) o[e] = f2b(b2f(d[e]) + b2f(xv[e]));
            *(u16x8*)((u16*)out + base) = o;
        }
    }
}

extern "C" void kernel_launch(void* const* d_in, const int* in_sizes, int n_in,
                              void* d_out, int out_size, void* d_ws, size_t ws_size,
                              hipStream_t stream) {
    char* ws = (char*)d_ws;
    float* stats = (float*)ws;                                   // 64 floats
    int*   flag  = (int*)(ws + 2048);
    float2* part = (float2*)(ws + 4096);                         // [4096] float2 = 32 KB
    u16* xb  = (u16*)(ws + 65536);                               // 4194304 u16
    u16* nwb = xb + (size_t)4194304;
    u16* nbb = nwb + 256;
    u16* qbb = nbb + 256;
    u16* pbb = qbb + 768;
    u16* pad = pbb + 256;
    u16* qwb = pad + 256;                                        // 196608
    u16* pwb = qwb + (size_t)196608;                             // 65536
    u16* tok = pwb + (size_t)65536;                              // [16384][256]
    u16* Qb  = tok + (size_t)16384 * 256;
    u16* Kb  = Qb  + (size_t)16384 * 256;
    u16* Vb  = Kb  + (size_t)16384 * 256;                        // [4][256][4096] (pos bit-swapped)
    u16* Upb = Vb  + (size_t)16384 * 256;                        // [16][256][4096] bf16 partials, [c][q]
    float* mlb = (float*)(Upb + (size_t)16 * 256 * 4096);        // [16][4096] float2

    k_cvt   <<<dim3(5126), dim3(256), 0, stream>>>(d_in[0], xb, flag, part,
                                                   d_in[1], d_in[2], d_in[3], d_in[4], d_in[5], d_in[6],
                                                   nwb, nbb, qwb, qbb, pwb, pbb);
    k_statsf<<<dim3(32), dim3(64), 0, stream>>>(part, stats);
    k_tok   <<<dim3(64, 4, 4), dim3(256), 0, stream>>>(xb, nwb, nbb, stats, tok);
    k_qkv   <<<dim3(128, 6), dim3(256), 0, stream>>>(tok, qwb, qbb, Qb, Kb, Vb);
    k_attn  <<<dim3(32, 4, 4), dim3(256), 0, stream>>>(Qb, Kb, Vb, Upb, mlb);
    k_proj  <<<dim3(256), dim3(256), 0, stream>>>(Upb, mlb, pwb, pbb, xb, d_out, flag);
}

// Round 9
// 204.685 us; speedup vs baseline: 1.2989x; 1.2989x over previous
//
#include <hip/hip_runtime.h>
#include <math.h>

typedef unsigned short u16;
typedef __bf16 bf16x8 __attribute__((ext_vector_type(8)));
typedef u16    u16x8  __attribute__((ext_vector_type(8)));
typedef float  f32x4  __attribute__((ext_vector_type(4)));
typedef float  f32x16 __attribute__((ext_vector_type(16)));

__device__ __forceinline__ float b2f(u16 u) {
    union { unsigned u; float f; } x; x.u = ((unsigned)u) << 16; return x.f;
}
__device__ __forceinline__ u16 f2b(float f) {
    union { float f; unsigned u; } x; x.f = f;
    unsigned r = x.u + 0x7FFFu + ((x.u >> 16) & 1u);   // RNE
    return (u16)(r >> 16);
}
__device__ __forceinline__ f32x4 mfma16(bf16x8 a, bf16x8 b, f32x4 c) {
    return __builtin_amdgcn_mfma_f32_16x16x32_bf16(a, b, c, 0, 0, 0);
}
__device__ __forceinline__ f32x16 mfma32(bf16x8 a, bf16x8 b, f32x16 c) {
    return __builtin_amdgcn_mfma_f32_32x32x16_bf16(a, b, c, 0, 0, 0);
}
__device__ __forceinline__ void dma16(const void* g, void* l) {
    __builtin_amdgcn_global_load_lds((const __attribute__((address_space(1))) void*)g,
                                     (__attribute__((address_space(3))) void*)l, 16, 0, 0);
}
// per-wave dtype vote on 64 fixed words: 1 = fp32, 0 = bf16
__device__ __forceinline__ int dtype_vote(const unsigned* w) {
    unsigned v = w[threadIdx.x & 63];
    unsigned e = ((v & 0xFFFFu) >> 7) & 0xFFu;
    unsigned long long m = __ballot(e >= 0x60u && e <= 0x8Fu);
    return (__popcll(m) >= 32) ? 0 : 1;
}

#define QSCALE 0.09016844f   // (1/16) * log2(e): softmax in base-2 domain

// ---------------------------------------------------------------- fused convert: x (blocks <4096) + params (>=4096)
__global__ __launch_bounds__(256) void k_cvt(const void* __restrict__ xsrc, u16* __restrict__ xdst,
                                             int* __restrict__ flag, float2* __restrict__ part,
                                             const void* s0, const void* s1, const void* s2,
                                             const void* s3, const void* s4, const void* s5,
                                             u16* d0, u16* d1, u16* d2, u16* d3, u16* d4, u16* d5) {
    if (blockIdx.x >= 4096) {
        const int f = dtype_vote((const unsigned*)s2);
        const int i = (blockIdx.x - 4096) * 256 + threadIdx.x;
        const void* s; u16* d; int j;
        if      (i < 256)    { s = s0; d = d0; j = i; }
        else if (i < 512)    { s = s1; d = d1; j = i - 256; }
        else if (i < 197120) { s = s2; d = d2; j = i - 512; }
        else if (i < 197888) { s = s3; d = d3; j = i - 197120; }
        else if (i < 263424) { s = s4; d = d4; j = i - 197888; }
        else if (i < 263680) { s = s5; d = d5; j = i - 263424; }
        else return;
        if (f) d[j] = f2b(((const float*)s)[j]);
        else   d[j] = ((const u16*)s)[j];
        return;
    }
    const int f = dtype_vote((const unsigned*)xsrc);
    if (blockIdx.x == 0 && threadIdx.x == 0) *flag = f;
    const int i = (blockIdx.x * 256 + threadIdx.x) * 4;
    u16 o[4];
    if (f) {
        float4 v = *(const float4*)((const float*)xsrc + i);
        o[0] = f2b(v.x); o[1] = f2b(v.y); o[2] = f2b(v.z); o[3] = f2b(v.w);
    } else {
        uint2 v = *(const uint2*)((const u16*)xsrc + i);
        o[0] = (u16)(v.x & 0xFFFF); o[1] = (u16)(v.x >> 16);
        o[2] = (u16)(v.y & 0xFFFF); o[3] = (u16)(v.y >> 16);
    }
    unsigned lo = (unsigned)o[0] | ((unsigned)o[1] << 16);
    unsigned hi = (unsigned)o[2] | ((unsigned)o[3] << 16);
    *(uint2*)(xdst + i) = make_uint2(lo, hi);
    float s = 0.f, ss = 0.f;
#pragma unroll
    for (int e = 0; e < 4; e++) { float x = b2f(o[e]); s += x; ss += x * x; }
#pragma unroll
    for (int d = 1; d < 64; d <<= 1) { s += __shfl_xor(s, d, 64); ss += __shfl_xor(ss, d, 64); }
    __shared__ float rs[4], rss[4];
    const int wv = threadIdx.x >> 6;
    if ((threadIdx.x & 63) == 0) { rs[wv] = s; rss[wv] = ss; }
    __syncthreads();
    if (threadIdx.x == 0)
        part[blockIdx.x] = make_float2(rs[0] + rs[1] + rs[2] + rs[3],
                                       rss[0] + rss[1] + rss[2] + rss[3]);
}

// ---------------------------------------------------------------- finalize group-norm stats
__global__ __launch_bounds__(64) void k_statsf(const float2* __restrict__ part, float* __restrict__ stats) {
    const int g = blockIdx.x, lane = threadIdx.x;
    float2 a = part[g * 128 + lane], b = part[g * 128 + 64 + lane];
    float s = a.x + b.x, ss = a.y + b.y;
#pragma unroll
    for (int d = 1; d < 64; d <<= 1) { s += __shfl_xor(s, d, 64); ss += __shfl_xor(ss, d, 64); }
    if (lane == 0) {
        float mean = s * (1.f / 131072.f);
        float var = fmaxf(ss * (1.f / 131072.f) - mean * mean, 0.f);
        stats[g] = mean;
        stats[32 + g] = rsqrtf(var + 1e-5f);
    }
}

// ---------------------------------------------------------------- normalize + transpose to tokens [b][n][c]
__global__ __launch_bounds__(256) void k_tok(const u16* __restrict__ x, const u16* __restrict__ nw,
                                             const u16* __restrict__ nb, const float* __restrict__ stats,
                                             u16* __restrict__ tok) {
    const int b = blockIdx.z, c0 = blockIdx.y * 64, p0 = blockIdx.x * 64;
    __shared__ u16 t[64][72];
    const int cl = threadIdx.x >> 2, seg = threadIdx.x & 3;
    const int c = c0 + cl;
    const int g = c >> 5;
    const float mean = stats[b * 8 + g], rstd = stats[32 + b * 8 + g];
    const float scale = b2f(nw[c]) * rstd;
    const float shift = b2f(nb[c]) - mean * scale;
    const u16* xp = x + ((size_t)(b * 256 + c)) * 4096 + p0 + seg * 16;
#pragma unroll
    for (int h = 0; h < 2; h++) {
        bf16x8 v = *(const bf16x8*)(xp + h * 8);
#pragma unroll
        for (int j = 0; j < 8; j++)
            t[seg * 16 + h * 8 + j][cl] = f2b((float)v[j] * scale + shift);
    }
    __syncthreads();
    u16x8 o0, o1;
#pragma unroll
    for (int j = 0; j < 8; j++) { o0[j] = t[cl][seg * 16 + j]; o1[j] = t[cl][seg * 16 + 8 + j]; }
    u16* op = tok + ((size_t)(b * 4096 + p0 + cl)) * 256 + c0 + seg * 16;
    *(u16x8*)op = o0;
    *((u16x8*)op + 1) = o1;
}

// ---------------------------------------------------------------- QKV GEMM, coalesced LDS-transposed epilogue
__global__ __launch_bounds__(256) void k_qkv(const u16* __restrict__ A, const u16* __restrict__ W,
                                             const u16* __restrict__ bias,
                                             u16* __restrict__ Qo, u16* __restrict__ Ko, u16* __restrict__ Vt) {
    const int m0 = blockIdx.x * 128, n0 = blockIdx.y * 128;
    const int cls = blockIdx.y >> 1, sub = (blockIdx.y & 1) * 128;
    const int b = m0 >> 12, p0 = m0 & 4095;
    const int tid = threadIdx.x, w = tid >> 6, lane = tid & 63, l15 = lane & 15, l4 = lane >> 4;
    const int wm = w >> 1, wn = w & 1;
    __shared__ __attribute__((aligned(16))) char QL[32768];
    u16* At = (u16*)QL;              // [128][64]
    u16* Bt = (u16*)(QL + 16384);    // [128][64]
    u16* E  = (u16*)QL;              // [128][128] epilogue reuse
    f32x4 acc[4][4];
    const f32x4 z = {0.f, 0.f, 0.f, 0.f};
#pragma unroll
    for (int i = 0; i < 4; i++)
#pragma unroll
        for (int j = 0; j < 4; j++) acc[i][j] = z;

    for (int kt = 0; kt < 4; kt++) {
        const int k0 = kt * 64;
#pragma unroll
        for (int i = 0; i < 4; i++) {
            int v = tid + i * 256;
            int row = v >> 3, c8 = v & 7;
            int swz = (c8 ^ (row & 7)) << 3;
            *(u16x8*)(&At[row * 64 + swz]) = *(const u16x8*)(A + (size_t)(m0 + row) * 256 + k0 + c8 * 8);
            *(u16x8*)(&Bt[row * 64 + swz]) = *(const u16x8*)(W + (size_t)(n0 + row) * 256 + k0 + c8 * 8);
        }
        __syncthreads();
#pragma unroll
        for (int ks = 0; ks < 2; ks++) {
            const int sc = ((ks * 4 + l4) ^ (l15 & 7)) << 3;
            bf16x8 af[4], bfr[4];
#pragma unroll
            for (int i = 0; i < 4; i++) {
                af[i]  = *(const bf16x8*)(&At[(wm * 64 + i * 16 + l15) * 64 + sc]);
                bfr[i] = *(const bf16x8*)(&Bt[(wn * 64 + i * 16 + l15) * 64 + sc]);
            }
#pragma unroll
            for (int i = 0; i < 4; i++)
#pragma unroll
                for (int j = 0; j < 4; j++) acc[i][j] = mfma16(af[i], bfr[j], acc[i][j]);
        }
        __syncthreads();
    }

    const float sf = (cls == 0) ? QSCALE : 1.f;
#pragma unroll
    for (int j = 0; j < 4; j++) {
        const int nl = wn * 64 + j * 16 + l15;
        const float bia = b2f(bias[n0 + nl]);
#pragma unroll
        for (int i = 0; i < 4; i++) {
#pragma unroll
            for (int r = 0; r < 4; r++) {
                const int ml = wm * 64 + i * 16 + l4 * 4 + r;
                const u16 val = f2b((acc[i][j][r] + bia) * sf);
                if (cls < 2) {
                    E[ml * 128 + (((nl >> 3) ^ (ml & 7)) << 3) + (nl & 7)] = val;
                } else {
                    int ps = ml ^ ((((ml >> 2) ^ (ml >> 3)) & 1) * 12);   // swap bits 2<->3
                    E[nl * 128 + (((ps >> 3) ^ (nl & 7)) << 3) + (ps & 7)] = val;
                }
            }
        }
    }
    __syncthreads();
    const int row = tid >> 1, half = tid & 1;
    u16* dst = (cls == 0) ? (Qo + (size_t)(m0 + row) * 256 + sub)
             : (cls == 1) ? (Ko + (size_t)(m0 + row) * 256 + sub)
                          : (Vt + (size_t)(b * 256 + sub + row) * 4096 + p0);
#pragma unroll
    for (int k = 0; k < 8; k++) {
        const int chunk = half * 8 + k;
        u16x8 v = *(const u16x8*)(&E[row * 128 + ((chunk ^ (row & 7)) << 3)]);
        *(u16x8*)(dst + chunk * 8) = v;
    }
}

// ---------------------------------------------------------------- flash attention: S^T trick, sync staging, [c][q] epilogue
// grid (32 qtiles x128q, 4 b, 4 splits); block 256 = 4 waves x 32 q; Bc=32; 32 iters.
__global__ __launch_bounds__(256, 2) void k_attn(const u16* __restrict__ Q, const u16* __restrict__ K,
                                                 const u16* __restrict__ Vt,
                                                 u16* __restrict__ Up, float* __restrict__ ml) {
    const int qt = blockIdx.x, b = blockIdx.y, sp = blockIdx.z;
    const int tid = threadIdx.x, w = tid >> 6, lane = tid & 63;
    const int l31 = lane & 31, h = lane >> 5;
    const int qcol = qt * 128 + w * 32 + l31;

    __shared__ __attribute__((aligned(16))) u16 KT[32 * 256];   // [j][c] swizzled
    __shared__ __attribute__((aligned(16))) u16 VT[256 * 32];   // [c][t] swizzled

    bf16x8 aq[16];
    {
        const u16* qp = Q + ((size_t)(b * 4096 + qcol)) * 256 + h * 8;
#pragma unroll
        for (int kb = 0; kb < 16; kb++) aq[kb] = *(const bf16x8*)(qp + kb * 16);
    }
    f32x16 acc[8];
#pragma unroll
    for (int ct = 0; ct < 8; ct++)
#pragma unroll
        for (int r = 0; r < 16; r++) acc[ct][r] = 0.f;
    float m_i = -3e38f, l_i = 0.f;

    const u16* Kg0 = K + (size_t)(b * 4096 + sp * 1024) * 256;
    const u16* Vg0 = Vt + (size_t)b * 256 * 4096 + sp * 1024;
    const int wb = (tid & 192) * 8;

    for (int kt = 0; kt < 32; kt++) {
        {
            const u16* Kg = Kg0 + (size_t)kt * 32 * 256;
#pragma unroll
            for (int i = 0; i < 4; i++) {
                int q = i * 256 + tid;
                int row = q >> 5, c = q & 31;
                dma16(Kg + row * 256 + ((c ^ row) << 3), &KT[i * 2048 + wb]);
            }
            const u16* Vg = Vg0 + kt * 32;
#pragma unroll
            for (int i = 0; i < 4; i++) {
                int q = i * 256 + tid;
                int row = q >> 2, c = q & 3;
                dma16(Vg + (size_t)row * 4096 + ((c ^ ((row >> 3) & 3)) << 3), &VT[i * 2048 + wb]);
            }
        }
        __syncthreads();

        // ---- S^T = K Q^T
        f32x16 st;
#pragma unroll
        for (int r = 0; r < 16; r++) st[r] = 0.f;
#pragma unroll
        for (int kb = 0; kb < 16; kb++) {
            bf16x8 bk = *(const bf16x8*)(&KT[l31 * 256 + (((kb * 2 + h) ^ l31) << 3)]);
            st = mfma32(bk, aq[kb], st);
        }

        // ---- per-lane online softmax (base-2 domain)
        float mx = st[0];
#pragma unroll
        for (int r = 1; r < 16; r++) mx = fmaxf(mx, st[r]);
        mx = fmaxf(mx, __shfl_xor(mx, 32, 64));
        if (__any(mx > m_i + 4.f)) {
            const float m_new = fmaxf(m_i, mx);
            const float al = __builtin_amdgcn_exp2f(m_i - m_new);
#pragma unroll
            for (int ct = 0; ct < 8; ct++)
#pragma unroll
                for (int r = 0; r < 16; r++) acc[ct][r] *= al;
            l_i *= al;
            m_i = m_new;
        }
        float sum = 0.f;
#pragma unroll
        for (int r = 0; r < 16; r++) {
            st[r] = __builtin_amdgcn_exp2f(st[r] - m_i);
            sum += st[r];
        }
        sum += __shfl_xor(sum, 32, 64);
        l_i += sum;

        union { u16x8 u; bf16x8 bv; } p0, p1;
#pragma unroll
        for (int e = 0; e < 8; e++) { p0.u[e] = f2b(st[e]); p1.u[e] = f2b(st[8 + e]); }

        // ---- acc += V^T P^T
#pragma unroll
        for (int ct = 0; ct < 8; ct++) {
            bf16x8 av0 = *(const bf16x8*)(&VT[(ct * 32 + l31) * 32 + ((h ^ (l31 >> 3)) << 3)]);
            acc[ct] = mfma32(av0, p0.bv, acc[ct]);
            bf16x8 av1 = *(const bf16x8*)(&VT[(ct * 32 + l31) * 32 + (((2 + h) ^ (l31 >> 3)) << 3)]);
            acc[ct] = mfma32(av1, p1.bv, acc[ct]);
        }
        __syncthreads();
    }

    // ---- epilogue: (m,l) + unnormalized partial O^T [c][q]
    if (h == 0)
        ((float2*)ml)[(size_t)(sp * 4 + b) * 4096 + qcol] = make_float2(m_i, l_i);
    u16* up = Up + (size_t)(sp * 4 + b) * 256 * 4096 + qcol;
#pragma unroll
    for (int ct = 0; ct < 8; ct++) {
#pragma unroll
        for (int r = 0; r < 16; r++) {
            const int c = ct * 32 + (r & 3) + 8 * (r >> 2) + 4 * h;
            up[(size_t)c * 4096] = f2b(acc[ct][r]);
        }
    }
}

// ---------------------------------------------------------------- proj GEMM: fused ml-combine (Up[c][q], vector loads) + residual
// grid (256): 64 m-rows x full N=256 per block.
__global__ __launch_bounds__(256) void k_proj(const u16* __restrict__ Up, const float* __restrict__ ml,
                                              const u16* __restrict__ W, const u16* __restrict__ bias,
                                              const u16* __restrict__ x, void* __restrict__ out,
                                              const int* __restrict__ flag) {
    const int f32out = *flag;
    const int m0 = blockIdx.x * 64;
    const int b = m0 >> 12, q0 = m0 & 4095;
    const int tid = threadIdx.x, w = tid >> 6, lane = tid & 63, l15 = lane & 15, l4 = lane >> 4;
    const int wm = w >> 1, wn = w & 1;
    __shared__ __attribute__((aligned(16))) char PL[40960];
    u16* At = (u16*)PL;            // [64][64]
    u16* Bt = (u16*)(PL + 8192);   // [256][64]
    u16* Ot = (u16*)PL;            // [256][64] epilogue reuse
    __shared__ float4 W4s[64];

    if (tid < 64) {
        const int q = q0 + tid;
        float m_s[4], l_s[4];
#pragma unroll
        for (int s = 0; s < 4; s++) {
            float2 v = ((const float2*)ml)[(size_t)(s * 4 + b) * 4096 + q];
            m_s[s] = v.x; l_s[s] = v.y;
        }
        float M = fmaxf(fmaxf(m_s[0], m_s[1]), fmaxf(m_s[2], m_s[3]));
        float L = 0.f, e[4];
#pragma unroll
        for (int s = 0; s < 4; s++) { e[s] = __builtin_amdgcn_exp2f(m_s[s] - M); L += l_s[s] * e[s]; }
        float inv = 1.f / fmaxf(L, 1e-30f);
        W4s[tid] = make_float4(e[0] * inv, e[1] * inv, e[2] * inv, e[3] * inv);
    }
    __syncthreads();

    // per-thread fixed 8-q chunk; combine weights preloaded to registers
    const int qch = (tid & 7) * 8;
    float wg0[8], wg1[8], wg2[8], wg3[8];
#pragma unroll
    for (int j = 0; j < 8; j++) {
        float4 wv = W4s[qch + j];
        wg0[j] = wv.x; wg1[j] = wv.y; wg2[j] = wv.z; wg3[j] = wv.w;
    }

    f32x4 acc[2][8];
    const f32x4 z = {0.f, 0.f, 0.f, 0.f};
#pragma unroll
    for (int i = 0; i < 2; i++)
#pragma unroll
        for (int j = 0; j < 8; j++) acc[i][j] = z;

    for (int kt = 0; kt < 4; kt++) {
        const int k0 = kt * 64;
        // ---- A-staging: combine 4 splits from Up[c][q] with u16x8 loads along q
#pragma unroll
        for (int u2 = 0; u2 < 2; u2++) {
            const int c = u2 * 32 + (tid >> 3);          // 0..63
            const u16* pb = Up + (size_t)(b * 256 + k0 + c) * 4096 + q0 + qch;
            u16x8 v0 = *(const u16x8*)(pb);
            u16x8 v1 = *(const u16x8*)(pb + (size_t)4 * 256 * 4096);
            u16x8 v2 = *(const u16x8*)(pb + (size_t)8 * 256 * 4096);
            u16x8 v3 = *(const u16x8*)(pb + (size_t)12 * 256 * 4096);
#pragma unroll
            for (int e = 0; e < 8; e++) {
                const float f = b2f(v0[e]) * wg0[e] + b2f(v1[e]) * wg1[e]
                              + b2f(v2[e]) * wg2[e] + b2f(v3[e]) * wg3[e];
                const int q = qch + e;
                At[q * 64 + (((c >> 3) ^ (q & 7)) << 3) + (c & 7)] = f2b(f);
            }
        }
        // ---- B-staging: proj_w [256][64]
#pragma unroll
        for (int i = 0; i < 8; i++) {
            int v = i * 256 + tid;
            int row = v >> 3, c8 = v & 7;
            *(u16x8*)(&Bt[row * 64 + ((c8 ^ (row & 7)) << 3)]) =
                *(const u16x8*)(W + (size_t)row * 256 + k0 + c8 * 8);
        }
        __syncthreads();
#pragma unroll
        for (int ks = 0; ks < 2; ks++) {
            const int sc = ((ks * 4 + l4) ^ (l15 & 7)) << 3;
            bf16x8 af[2], bfr[8];
#pragma unroll
            for (int i = 0; i < 2; i++)
                af[i] = *(const bf16x8*)(&At[(wm * 32 + i * 16 + l15) * 64 + sc]);
#pragma unroll
            for (int j = 0; j < 8; j++)
                bfr[j] = *(const bf16x8*)(&Bt[(wn * 128 + j * 16 + l15) * 64 + sc]);
#pragma unroll
            for (int i = 0; i < 2; i++)
#pragma unroll
                for (int j = 0; j < 8; j++) acc[i][j] = mfma16(af[i], bfr[j], acc[i][j]);
        }
        __syncthreads();
    }

#pragma unroll
    for (int j = 0; j < 8; j++) {
        const int n = wn * 128 + j * 16 + l15;
        const float bia = b2f(bias[n]);
#pragma unroll
        for (int i = 0; i < 2; i++) {
#pragma unroll
            for (int r = 0; r < 4; r++) {
                const int p = wm * 32 + i * 16 + l4 * 4 + r;
                Ot[n * 64 + ((((p >> 3) ^ (n & 7)) << 3)) + (p & 7)] = f2b(acc[i][j][r] + bia);
            }
        }
    }
    __syncthreads();
    const int ps = (tid & 7) * 8;
#pragma unroll
    for (int v = 0; v < 8; v++) {
        const int n = v * 32 + (tid >> 3);
        u16x8 d = *(const u16x8*)(&Ot[n * 64 + ((((ps >> 3) ^ (n & 7)) << 3))]);
        const size_t base = ((size_t)(b * 256 + n)) * 4096 + q0 + ps;
        u16x8 xv = *(const u16x8*)(x + base);
        if (f32out) {
            float4 o0, o1;
#pragma unroll
            for (int e = 0; e < 4; e++) o0[e] = b2f(d[e]) + b2f(xv[e]);
#pragma unroll
            for (int e = 0; e < 4; e++) o1[e] = b2f(d[4 + e]) + b2f(xv[4 + e]);
            *(float4*)((float*)out + base) = o0;
            *(float4*)((float*)out + base + 4) = o1;
        } else {
            u16x8 o;
#pragma unroll
            for (int e = 0; e < 8; e++) o[e] = f2b(b2f(d[e]) + b2f(xv[e]));
            *(u16x8*)((u16*)out + base) = o;
        }
    }
}

extern "C" void kernel_launch(void* const* d_in, const int* in_sizes, int n_in,
                              void* d_out, int out_size, void* d_ws, size_t ws_size,
                              hipStream_t stream) {
    char* ws = (char*)d_ws;
    float* stats = (float*)ws;                                   // 64 floats
    int*   flag  = (int*)(ws + 2048);
    float2* part = (float2*)(ws + 4096);                         // [4096] float2 = 32 KB
    u16* xb  = (u16*)(ws + 65536);                               // 4194304 u16
    u16* nwb = xb + (size_t)4194304;
    u16* nbb = nwb + 256;
    u16* qbb = nbb + 256;
    u16* pbb = qbb + 768;
    u16* pad = pbb + 256;
    u16* qwb = pad + 256;                                        // 196608
    u16* pwb = qwb + (size_t)196608;                             // 65536
    u16* tok = pwb + (size_t)65536;                              // [16384][256]
    u16* Qb  = tok + (size_t)16384 * 256;
    u16* Kb  = Qb  + (size_t)16384 * 256;
    u16* Vb  = Kb  + (size_t)16384 * 256;                        // [4][256][4096] (pos bit-swapped)
    u16* Upb = Vb  + (size_t)16384 * 256;                        // [16][256][4096] bf16 partials, [c][q]
    float* mlb = (float*)(Upb + (size_t)16 * 256 * 4096);        // [16][4096] float2

    k_cvt   <<<dim3(5126), dim3(256), 0, stream>>>(d_in[0], xb, flag, part,
                                                   d_in[1], d_in[2], d_in[3], d_in[4], d_in[5], d_in[6],
                                                   nwb, nbb, qwb, qbb, pwb, pbb);
    k_statsf<<<dim3(32), dim3(64), 0, stream>>>(part, stats);
    k_tok   <<<dim3(64, 4, 4), dim3(256), 0, stream>>>(xb, nwb, nbb, stats, tok);
    k_qkv   <<<dim3(128, 6), dim3(256), 0, stream>>>(tok, qwb, qbb, Qb, Kb, Vb);
    k_attn  <<<dim3(32, 4, 4), dim3(256), 0, stream>>>(Qb, Kb, Vb, Upb, mlb);
    k_proj  <<<dim3(256), dim3(256), 0, stream>>>(Upb, mlb, pwb, pbb, xb, d_out, flag);
}